// Round 1
// baseline (641.916 us; speedup 1.0000x reference)
//
#include <hip/hip_runtime.h>
#include <hip/hip_bf16.h>
#include <stdint.h>

// GCN layer: out = D^-1/2 (A+I) D^-1/2 (x W + b)
// N=100000 nodes, E=3.2M edges, 256 -> 128 features.
// Pipeline: degree count -> rsqrt -> CSR build (scan+scatter) -> fp32 GEMM
// (h stored bf16-packed) -> wave-per-node gather aggregation (no output atomics).

__device__ __forceinline__ float bf_lo(uint32_t p) { return __uint_as_float(p << 16); }
__device__ __forceinline__ float bf_hi(uint32_t p) { return __uint_as_float(p & 0xffff0000u); }

__device__ __forceinline__ uint32_t f2bf(float f) {
  uint32_t u = __float_as_uint(f);
  return (u + 0x7fffu + ((u >> 16) & 1u)) >> 16;  // RNE
}
__device__ __forceinline__ uint32_t pack_bf16(float lo, float hi) {
  return (f2bf(hi) << 16) | f2bf(lo);
}

// ---- degree count ----
__global__ void k_count(const int* __restrict__ rows, int E, int* __restrict__ deg) {
  int e = blockIdx.x * blockDim.x + threadIdx.x;
  if (e < E) atomicAdd(&deg[rows[e]], 1);
}

// ---- d^-1/2 (deg includes +1 self loop) ----
__global__ void k_dis(const int* __restrict__ deg, float* __restrict__ dis, int N) {
  int i = blockIdx.x * blockDim.x + threadIdx.x;
  if (i < N) dis[i] = rsqrtf((float)(deg[i] + 1));
}

// ---- scan step 1: per-1024-block sums ----
__global__ void k_blocksum(const int* __restrict__ deg, int N, int* __restrict__ partials) {
  __shared__ int tmp[256];
  int t = threadIdx.x;
  int idx0 = blockIdx.x * 1024 + t * 4;
  int s = 0;
  if (idx0 < N) {  // N % 4 == 0 so int4 never straddles N
    int4 v = *(const int4*)&deg[idx0];
    s = v.x + v.y + v.z + v.w;
  }
  tmp[t] = s; __syncthreads();
  for (int d = 128; d > 0; d >>= 1) {
    if (t < d) tmp[t] += tmp[t + d];
    __syncthreads();
  }
  if (t == 0) partials[blockIdx.x] = tmp[0];
}

// ---- scan step 2: exclusive scan of partials (single block, nb <= 1024) ----
__global__ void k_scanp(int* __restrict__ partials, int nb) {
  __shared__ int s[1024];
  int t = threadIdx.x;
  int v = (t < nb) ? partials[t] : 0;
  s[t] = v; __syncthreads();
  for (int d = 1; d < 1024; d <<= 1) {
    int u = (t >= d) ? s[t - d] : 0;
    __syncthreads();
    s[t] += u;
    __syncthreads();
  }
  if (t < nb) partials[t] = s[t] - v;  // exclusive
}

// ---- scan step 3: per-element offsets ----
__global__ void k_offsets(const int* __restrict__ deg, const int* __restrict__ partials,
                          int N, int* __restrict__ offs) {
  __shared__ int tmp[256];
  int t = threadIdx.x;
  int idx0 = blockIdx.x * 1024 + t * 4;
  int4 v = make_int4(0, 0, 0, 0);
  if (idx0 < N) v = *(const int4*)&deg[idx0];
  int total = v.x + v.y + v.z + v.w;
  tmp[t] = total; __syncthreads();
  for (int d = 1; d < 256; d <<= 1) {
    int u = (t >= d) ? tmp[t - d] : 0;
    __syncthreads();
    tmp[t] += u;
    __syncthreads();
  }
  int ex = tmp[t] - total + partials[blockIdx.x];
  if (idx0 < N) {
    int4 o;
    o.x = ex; o.y = ex + v.x; o.z = ex + v.x + v.y; o.w = ex + v.x + v.y + v.z;
    *(int4*)&offs[idx0] = o;
  }
}

// ---- CSR bucket scatter ----
__global__ void k_scatter(const int* __restrict__ rows, const int* __restrict__ cols, int E,
                          const int* __restrict__ offs, int* __restrict__ cursor,
                          int* __restrict__ csr_col) {
  int e = blockIdx.x * blockDim.x + threadIdx.x;
  if (e < E) {
    int r = rows[e];
    int p = atomicAdd(&cursor[r], 1);
    csr_col[offs[r] + p] = cols[e];
  }
}

// ---- fp32 GEMM: h[m][n] = sum_k x[m][k] W[k][n] + b[n], stored bf16-packed ----
// block: 256 thr, tile M=64, N=128(full), K staged 64 at a time.
__launch_bounds__(256)
__global__ void k_gemm(const float* __restrict__ x, const float* __restrict__ W,
                       const float* __restrict__ bias, uint32_t* __restrict__ hu, int M) {
  __shared__ float xs[64][68];    // +4 pad
  __shared__ float ws[64][132];   // +4 pad
  int tid = threadIdx.x;
  int tx = tid & 31;   // covers cols {2tx, 2tx+1, 2tx+64, 2tx+65}
  int ty = tid >> 5;   // covers rows ty + 8*i
  int m0 = blockIdx.x * 64;
  float acc[8][4];
#pragma unroll
  for (int i = 0; i < 8; ++i)
#pragma unroll
    for (int j = 0; j < 4; ++j) acc[i][j] = 0.0f;

  for (int k0 = 0; k0 < 256; k0 += 64) {
#pragma unroll
    for (int l = 0; l < 4; ++l) {           // x tile: 64x64 floats
      int li = l * 256 + tid;
      int r = li >> 4;
      int c = (li & 15) << 2;
      float4 v = make_float4(0.f, 0.f, 0.f, 0.f);
      int gm = m0 + r;
      if (gm < M) v = *(const float4*)&x[(size_t)gm * 256 + k0 + c];
      *(float4*)&xs[r][c] = v;
    }
#pragma unroll
    for (int l = 0; l < 8; ++l) {           // W tile: 64x128 floats
      int li = l * 256 + tid;
      int r = li >> 5;
      int c = (li & 31) << 2;
      *(float4*)&ws[r][c] = *(const float4*)&W[(size_t)(k0 + r) * 128 + c];
    }
    __syncthreads();
#pragma unroll 8
    for (int kk = 0; kk < 64; ++kk) {
      float a[8], w[4];
#pragma unroll
      for (int i = 0; i < 8; ++i) a[i] = xs[ty + 8 * i][kk];
      w[0] = ws[kk][2 * tx];
      w[1] = ws[kk][2 * tx + 1];
      w[2] = ws[kk][2 * tx + 64];
      w[3] = ws[kk][2 * tx + 65];
#pragma unroll
      for (int i = 0; i < 8; ++i) {
        acc[i][0] = fmaf(a[i], w[0], acc[i][0]);
        acc[i][1] = fmaf(a[i], w[1], acc[i][1]);
        acc[i][2] = fmaf(a[i], w[2], acc[i][2]);
        acc[i][3] = fmaf(a[i], w[3], acc[i][3]);
      }
    }
    __syncthreads();
  }
  float b0 = bias[2 * tx], b1 = bias[2 * tx + 1];
  float b2 = bias[2 * tx + 64], b3 = bias[2 * tx + 65];
#pragma unroll
  for (int i = 0; i < 8; ++i) {
    int m = m0 + ty + 8 * i;
    if (m < M) {
      hu[(size_t)m * 64 + tx]      = pack_bf16(acc[i][0] + b0, acc[i][1] + b1);
      hu[(size_t)m * 64 + tx + 32] = pack_bf16(acc[i][2] + b2, acc[i][3] + b3);
    }
  }
}

// ---- aggregation: one wave per node, lane holds features {2*lane, 2*lane+1} ----
__launch_bounds__(256)
__global__ void k_aggregate(const uint32_t* __restrict__ hu, const float* __restrict__ dis,
                            const int* __restrict__ offs, const int* __restrict__ csr_col,
                            float* __restrict__ out, int N, int E) {
  int wid = blockIdx.x * 4 + (threadIdx.x >> 6);
  int lane = threadIdx.x & 63;
  if (wid >= N) return;
  float di = dis[wid];
  uint32_t ps = hu[(size_t)wid * 64 + lane];
  float ax = di * bf_lo(ps);   // self loop contributes dis[i]*h[i] to the sum
  float ay = di * bf_hi(ps);
  int e = offs[wid];
  int end = (wid + 1 < N) ? offs[wid + 1] : E;
  for (; e + 1 < end; e += 2) {
    int c0 = csr_col[e], c1 = csr_col[e + 1];
    float w0 = dis[c0], w1 = dis[c1];
    uint32_t p0 = hu[(size_t)c0 * 64 + lane];
    uint32_t p1 = hu[(size_t)c1 * 64 + lane];
    ax += w0 * bf_lo(p0) + w1 * bf_lo(p1);
    ay += w0 * bf_hi(p0) + w1 * bf_hi(p1);
  }
  if (e < end) {
    int c = csr_col[e];
    float w = dis[c];
    uint32_t p = hu[(size_t)c * 64 + lane];
    ax += w * bf_lo(p);
    ay += w * bf_hi(p);
  }
  float2 o; o.x = di * ax; o.y = di * ay;
  *(float2*)&out[(size_t)wid * 128 + 2 * lane] = o;
}

// ---- fallback (small workspace): per-edge atomics ----
__launch_bounds__(256)
__global__ void k_selfinit(const uint32_t* __restrict__ hu, const float* __restrict__ dis,
                           float* __restrict__ out, int N) {
  int wid = blockIdx.x * 4 + (threadIdx.x >> 6);
  int lane = threadIdx.x & 63;
  if (wid >= N) return;
  float d2 = dis[wid] * dis[wid];
  uint32_t p = hu[(size_t)wid * 64 + lane];
  float2 o; o.x = d2 * bf_lo(p); o.y = d2 * bf_hi(p);
  *(float2*)&out[(size_t)wid * 128 + 2 * lane] = o;
}

__launch_bounds__(256)
__global__ void k_edge_atomic(const int* __restrict__ rows, const int* __restrict__ cols, int E,
                              const uint32_t* __restrict__ hu, const float* __restrict__ dis,
                              float* __restrict__ out) {
  int wid = blockIdx.x * 4 + (threadIdx.x >> 6);
  int lane = threadIdx.x & 63;
  if (wid >= E) return;
  int r = rows[wid], c = cols[wid];
  float w = dis[r] * dis[c];
  uint32_t p = hu[(size_t)c * 64 + lane];
  atomicAdd(&out[(size_t)r * 128 + 2 * lane], w * bf_lo(p));
  atomicAdd(&out[(size_t)r * 128 + 2 * lane + 1], w * bf_hi(p));
}

extern "C" void kernel_launch(void* const* d_in, const int* in_sizes, int n_in,
                              void* d_out, int out_size, void* d_ws, size_t ws_size,
                              hipStream_t stream) {
  const float* x    = (const float*)d_in[0];
  const int*   ei   = (const int*)d_in[1];
  const float* W    = (const float*)d_in[2];
  const float* bias = (const float*)d_in[3];
  float* out = (float*)d_out;

  const int N = in_sizes[0] / 256;   // 100000
  const int E = in_sizes[1] / 2;     // 3200000
  const int* rows = ei;
  const int* cols = ei + E;

  // workspace layout (256B aligned slices)
  size_t off = 0;
  auto alloc = [&](size_t bytes) -> void* {
    void* p = (char*)d_ws + off;
    off += (bytes + 255) & ~(size_t)255;
    return p;
  };
  uint32_t* hu     = (uint32_t*)alloc((size_t)N * 64 * 4);  // bf16-packed h
  float*    dis    = (float*)alloc((size_t)N * 4);
  int*      deg    = (int*)alloc((size_t)N * 4);
  int*      cursor = (int*)alloc((size_t)N * 4);
  int*      offs   = (int*)alloc(((size_t)N + 4) * 4);
  int*      parts  = (int*)alloc(1024 * 4);
  size_t small_end = off;
  int*      csr    = (int*)alloc((size_t)E * 4);
  bool full = (off <= ws_size);
  bool atomic_ok = (small_end <= ws_size);

  hipMemsetAsync(deg, 0, (size_t)N * 4, stream);
  k_count<<<(E + 255) / 256, 256, 0, stream>>>(rows, E, deg);
  k_dis<<<(N + 255) / 256, 256, 0, stream>>>(deg, dis, N);
  k_gemm<<<(N + 63) / 64, 256, 0, stream>>>(x, W, bias, hu, N);

  if (full) {
    int nb = (N + 1023) / 1024;
    k_blocksum<<<nb, 256, 0, stream>>>(deg, N, parts);
    k_scanp<<<1, 1024, 0, stream>>>(parts, nb);
    k_offsets<<<nb, 256, 0, stream>>>(deg, parts, N, offs);
    hipMemsetAsync(cursor, 0, (size_t)N * 4, stream);
    k_scatter<<<(E + 255) / 256, 256, 0, stream>>>(rows, cols, E, offs, cursor, csr);
    k_aggregate<<<(N + 3) / 4, 256, 0, stream>>>(hu, dis, offs, csr, out, N, E);
  } else if (atomic_ok) {
    k_selfinit<<<(N + 3) / 4, 256, 0, stream>>>(hu, dis, out, N);
    k_edge_atomic<<<(E + 3) / 4, 256, 0, stream>>>(rows, cols, E, hu, dis, out);
  }
}